// Round 12
// baseline (68.288 us; speedup 1.0000x reference)
//
#include <hip/hip_runtime.h>

#define NN 2048
#define GG 64
#define TS 128
#define NT (NN / TS)                 // 16 tiles
#define NPAIR (NT * (NT + 1) / 2)    // 136 tile pairs
#define MAXE 14336                   // per-image edge cap (est. E ~ 3000)
#define EBUF 3072                    // per-block LDS edge buffer
#define STH 512

typedef unsigned long long u64;
typedef unsigned short u16;
typedef unsigned int u32;

__device__ __forceinline__ float iou4(float4 a, float4 b) {
    float w = fminf(a.z, b.z) - fmaxf(a.x, b.x) + 1.0f;
    float h = fminf(a.w, b.w) - fmaxf(a.y, b.y) + 1.0f;
    w = fmaxf(w, 0.0f);
    h = fmaxf(h, 0.0f);
    float ov = w * h;
    float aa = (a.z - a.x + 1.0f) * (a.w - a.y + 1.0f);
    float ab = (b.z - b.x + 1.0f) * (b.w - b.y + 1.0f);
    return ov / (aa + ab - ov);
}

__device__ __forceinline__ float wredf(float v) {
    for (int o = 32; o > 0; o >>= 1) v += __shfl_down(v, o);
    return v;
}
__device__ __forceinline__ int wredi(int v) {
    for (int o = 32; o > 0; o >>= 1) v += __shfl_down(v, o);
    return v;
}

// selection order: earlier = higher score, tie -> lower original index (scores >= 0).
__device__ __forceinline__ bool earlier(u32 sa, int a, u32 sb, int b) {
    return (sa > sb) || (sa == sb && a < b);
}
__device__ __forceinline__ u64 make_key(u32 sbits, int j) {
    return ((u64)sbits << 32) | (u64)(NN - 1 - j);
}

// ---------------- K0: transpose proposals to SoA (coalesced everywhere after) ----------------
__global__ __launch_bounds__(STH) void prep_kernel(const int* __restrict__ gt_inds,
                                                   const float* __restrict__ props,
                                                   float4* __restrict__ sbox, float* __restrict__ ssc,
                                                   int* __restrict__ sgt) {
    __shared__ float pbL[NN * 5];        // 40 KB
    const int im = blockIdx.x, tid = threadIdx.x;
    const float4* pv = (const float4*)(props + (size_t)im * NN * 5);
    float4* pl4 = (float4*)pbL;
    for (int x = tid; x < NN * 5 / 4; x += STH) pl4[x] = pv[x];   // linear, coalesced
    __syncthreads();
    const int base = im * NN;
    const int* gbi = gt_inds + (size_t)im * NN;
    for (int j = tid; j < NN; j += STH) {
        sbox[base + j] = make_float4(pbL[j * 5], pbL[j * 5 + 1], pbL[j * 5 + 2], pbL[j * 5 + 3]);
        ssc[base + j] = pbL[j * 5 + 4];
        sgt[base + j] = gbi[j];
    }
}

// ---------------- K1: balanced LDS-tiled pair phase -> compact edge list ----------------
__global__ __launch_bounds__(256) void pair_kernel(const float4* __restrict__ sbox,
                                                   const float* __restrict__ ssc,
                                                   const int* __restrict__ sgt,
                                                   int* __restrict__ ecnt, u32* __restrict__ edges) {
    const int im = blockIdx.x / NPAIR;
    int q = blockIdx.x % NPAIR;
    int ta = 0;
    while (q >= NT - ta) { q -= NT - ta; ++ta; }
    const int tb = ta + q;
    const int base = im * NN;

    __shared__ float4 Abox[TS], Bbox[TS];
    __shared__ u32 Asc[TS], Bsc[TS];
    __shared__ int Ag[TS], Bg[TS];
    __shared__ u32 ebuf[EBUF];
    __shared__ int lcnt, gbase;
    const int tid = threadIdx.x;
    if (tid == 0) lcnt = 0;

    for (int t = tid; t < TS; t += 256) {
        Abox[t] = sbox[base + ta * TS + t];
        Asc[t] = __float_as_uint(ssc[base + ta * TS + t]);
        Ag[t] = sgt[base + ta * TS + t];
        Bbox[t] = sbox[base + tb * TS + t];
        Bsc[t] = __float_as_uint(ssc[base + tb * TS + t]);
        Bg[t] = sgt[base + tb * TS + t];
    }
    __syncthreads();

    const int pr = tid & (TS - 1);      // row in tile A
    const int half = tid >> 7;          // column half in tile B
    const float4 rb = Abox[pr];
    const u32 rs = Asc[pr];
    const int i = ta * TS + pr;
    int* ec = ecnt + im * 32;           // 128B-padded per-image counter
    u32* ge = edges + (size_t)im * MAXE;
    if (Ag[pr] >= 0) {
        #pragma unroll 4
        for (int k = 0; k < TS / 2; ++k) {
            int jl = half * (TS / 2) + k;
            if (ta == tb && jl <= pr) continue;   // each unordered pair once
            if (Bg[jl] < 0) continue;
            float v = iou4(rb, Bbox[jl]);
            if (v > 0.5f) {
                int j = tb * TS + jl;
                int late, early;
                if (earlier(rs, i, Bsc[jl], j)) { late = j; early = i; }
                else                            { late = i; early = j; }
                u32 packed = ((u32)late << 16) | (u32)early;
                int slot = atomicAdd(&lcnt, 1);            // LDS atomic
                if (slot < EBUF) ebuf[slot] = packed;
                else {                                      // spill (essentially never)
                    int gs = atomicAdd(ec, 1);
                    if (gs < MAXE) ge[gs] = packed;
                }
            }
        }
    }
    __syncthreads();
    const int n = min(lcnt, EBUF);
    if (tid == 0) gbase = (n > 0) ? atomicAdd(ec, n) : 0;   // one global atomic per block
    __syncthreads();
    for (int e = tid; e < n; e += 256) {
        int gidx = gbase + e;
        if (gidx < MAXE) ge[gidx] = ebuf[e];                // coalesced copy
    }
}

// ---------------- K2: CSR build + worklist fixpoint; writes st + CSR to ws ----------------
__global__ __launch_bounds__(STH) void fix_kernel(const int* __restrict__ sgt,
                                                  const int* __restrict__ ecnt, const u32* __restrict__ edges,
                                                  unsigned char* __restrict__ st_g,
                                                  u16* __restrict__ eoff_g, u16* __restrict__ ent_g) {
    __shared__ union { int cw[NN]; u16 wl[2][NN]; } uu;   // 8 KB (cw dead before wl used)
    __shared__ u16 eoff[NN + 2];          // 4.1 KB
    __shared__ u16 ent[MAXE];             // 28 KB
    __shared__ unsigned char st[NN];      // 2 KB
    __shared__ int wtot[STH / 64];
    __shared__ int s_cnt[2];

    const int im = blockIdx.x, tid = threadIdx.x;
    const int lane = tid & 63, wid = tid >> 6;
    const u32* ge = edges + (size_t)im * MAXE;
    volatile unsigned char* vst = st;

    if (tid == 0) { s_cnt[0] = 0; s_cnt[1] = 0; }
    if (tid == 0) { eoff[NN + 1] = 0; }
    for (int j = tid; j < NN; j += STH) {
        st[j] = (sgt[im * NN + j] >= 0) ? 0 : 2;
        uu.cw[j] = 0;
    }
    __syncthreads();

    // ---- build LDS CSR from the edge list ----
    const int E = min(ecnt[im * 32], MAXE);
    for (int e = tid; e < E; e += STH) atomicAdd(&uu.cw[ge[e] >> 16], 1);
    __syncthreads();
    {   // block-wide exclusive prefix sum over 2048 counts (4 per thread)
        int j0 = tid * 4;
        int c0 = uu.cw[j0], c1 = uu.cw[j0 + 1], c2 = uu.cw[j0 + 2], c3 = uu.cw[j0 + 3];
        int s = c0 + c1 + c2 + c3;
        int incl = s;
        for (int o = 1; o < 64; o <<= 1) {
            int v = __shfl_up(incl, o);
            if (lane >= o) incl += v;
        }
        if (lane == 63) wtot[wid] = incl;
        __syncthreads();
        int wpre = 0;
        for (int wq = 0; wq < wid; ++wq) wpre += wtot[wq];
        int excl = wpre + incl - s;
        eoff[j0] = (u16)excl;
        eoff[j0 + 1] = (u16)(excl + c0);
        eoff[j0 + 2] = (u16)(excl + c0 + c1);
        eoff[j0 + 3] = (u16)(excl + c0 + c1 + c2);
        if (tid == STH - 1) eoff[NN] = (u16)(excl + s);
        uu.cw[j0] = excl;
        uu.cw[j0 + 1] = excl + c0;
        uu.cw[j0 + 2] = excl + c0 + c1;
        uu.cw[j0 + 3] = excl + c0 + c1 + c2;
    }
    __syncthreads();
    for (int e = tid; e < E; e += STH) {
        u32 x = ge[e];
        int pos = atomicAdd(&uu.cw[x >> 16], 1);
        ent[pos] = (u16)(x & 0xffffu);
    }
    __syncthreads();                      // cw dead; wl[ ] (same storage) live below

    // ---- fixpoint round 1: full sweep, compact unresolved into worklist 0 ----
    for (int j = tid; j < NN; j += STH) {
        if (st[j] != 0) continue;
        int e0 = eoff[j], e1 = eoff[j + 1];
        bool anyK = false, anyU = false;
        for (int e = e0; e < e1; ++e) {
            unsigned char s = vst[ent[e]];
            anyK |= (s == 1);
            anyU |= (s == 0);
        }
        if (anyK) st[j] = 2;
        else if (!anyU) st[j] = 1;
        else { int pos = atomicAdd(&s_cnt[0], 1); uu.wl[0][pos] = (u16)j; }
    }
    __syncthreads();

    // ---- fixpoint rounds: worklist only, 3 relaxation sub-sweeps per barrier ----
    int src = 0;
    int nwl = s_cnt[0];
    while (nwl > 0) {
        #pragma unroll
        for (int r = 0; r < 2; ++r) {       // benign-race relaxations (monotone st)
            for (int w = tid; w < nwl; w += STH) {
                int j = uu.wl[src][w];
                if (st[j] != 0) continue;
                int e0 = eoff[j], e1 = eoff[j + 1];
                bool anyK = false, anyU = false;
                for (int e = e0; e < e1; ++e) {
                    unsigned char s = vst[ent[e]];
                    anyK |= (s == 1);
                    anyU |= (s == 0);
                }
                if (anyK) st[j] = 2;
                else if (!anyU) st[j] = 1;
            }
        }
        for (int w = tid; w < nwl; w += STH) {
            int j = uu.wl[src][w];
            if (st[j] != 0) continue;
            int e0 = eoff[j], e1 = eoff[j + 1];
            bool anyK = false, anyU = false;
            for (int e = e0; e < e1; ++e) {
                unsigned char s = vst[ent[e]];
                anyK |= (s == 1);
                anyU |= (s == 0);
            }
            if (anyK) st[j] = 2;
            else if (!anyU) st[j] = 1;
            else { int pos = atomicAdd(&s_cnt[src ^ 1], 1); uu.wl[src ^ 1][pos] = (u16)j; }
        }
        __syncthreads();
        nwl = s_cnt[src ^ 1];
        if (tid == 0) s_cnt[src] = 0;
        src ^= 1;
        __syncthreads();
    }

    // ---- export st + CSR (coalesced u32 stores) ----
    u32* stg = (u32*)(st_g + (size_t)im * NN);
    for (int x = tid; x < NN / 4; x += STH) stg[x] = ((u32*)st)[x];
    u32* eg = (u32*)(eoff_g + (size_t)im * (NN + 2));
    for (int x = tid; x < (NN + 2) / 2; x += STH) eg[x] = ((u32*)eoff)[x];
    u32* ng = (u32*)(ent_g + (size_t)im * MAXE);
    for (int x = tid; x < (E + 1) / 2; x += STH) ng[x] = ((u32*)ent)[x];
}

// ---------------- K3: attribution + accumulation + fused finalize ----------------
__global__ __launch_bounds__(STH) void attr_kernel(const int* __restrict__ sgt_g,
                                                   const float* __restrict__ gt_boxes,
                                                   const float4* __restrict__ sbox,
                                                   const float* __restrict__ ssc,
                                                   const int* __restrict__ ecnt,
                                                   const unsigned char* __restrict__ st_g,
                                                   const u16* __restrict__ eoff_g, const u16* __restrict__ ent_g,
                                                   float* __restrict__ acc, u32* __restrict__ ctr2,
                                                   float* __restrict__ out, int B) {
    __shared__ u32 scoreL[NN];            // 8 KB
    __shared__ float sumA[NN];            // 8 KB
    __shared__ u32 cntA[NN];              // 8 KB
    __shared__ u16 eoff[NN + 2];          // 4.1 KB
    __shared__ u16 ent[MAXE];             // 28 KB
    __shared__ unsigned char st[NN];      // 2 KB
    __shared__ signed char gtL[NN];       // 2 KB (g clamped to [-1, 63])
    __shared__ u32 hkw[NN / 32];          // 256 B bitmask: kept box suppressed someone
    __shared__ float4 gtb[GG];            // 1 KB
    __shared__ u64 firstk[GG];            // 0.5 KB
    __shared__ u64 s_minkey;
    __shared__ int s_pos, s_qcnt, s_pcnt;
    __shared__ float s_tpush, s_tpull;

    const int im = blockIdx.x, tid = threadIdx.x;
    const int lane = tid & 63;
    const int base = im * NN;

    if (tid == 0) { s_pos = 0; s_qcnt = 0; s_pcnt = 0; s_tpush = 0.f; s_tpull = 0.f; s_minkey = ~0ull; }
    if (tid < GG) {
        firstk[tid] = 0ull;
        gtb[tid] = ((const float4*)(gt_boxes + (size_t)im * GG * 4))[tid];
    }
    if (tid < NN / 32) hkw[tid] = 0u;

    // ---- import state (coalesced) ----
    const int E = min(ecnt[im * 32], MAXE);
    const u32* stg = (const u32*)(st_g + (size_t)im * NN);
    for (int x = tid; x < NN / 4; x += STH) ((u32*)st)[x] = stg[x];
    const u32* eg = (const u32*)(eoff_g + (size_t)im * (NN + 2));
    for (int x = tid; x < (NN + 2) / 2; x += STH) ((u32*)eoff)[x] = eg[x];
    const u32* ng = (const u32*)(ent_g + (size_t)im * MAXE);
    for (int x = tid; x < (E + 1) / 2; x += STH) ((u32*)ent)[x] = ng[x];
    int lpos = 0;
    for (int j = tid; j < NN; j += STH) {
        scoreL[j] = __float_as_uint(ssc[base + j]);
        int g = sgt_g[base + j];
        gtL[j] = (signed char)((g < 0) ? -1 : g);
        lpos += (g >= 0) ? 1 : 0;
        sumA[j] = 0.f; cntA[j] = 0;
    }
    lpos = wredi(lpos);
    if (lane == 0 && lpos) atomicAdd(&s_pos, lpos);
    __syncthreads();

    // ---- pass 1: kept bookkeeping + killer attribution ----
    for (int j = tid; j < NN; j += STH) {
        int g = gtL[j];
        if (st[j] == 1) {
            u64 kj = make_key(scoreL[j], j);
            atomicMin(&s_minkey, kj);
            atomicMax(&firstk[g], kj);
        } else if (g >= 0) {
            int e0 = eoff[j], e1 = eoff[j + 1];
            int ki = -1; u32 ks = 0;
            for (int e = e0; e < e1; ++e) {
                int ii = ent[e];
                if (st[ii] == 1 && (ki < 0 || earlier(scoreL[ii], ii, ks, ki))) { ki = ii; ks = scoreL[ii]; }
            }
            if (ki < 0) continue;         // cannot happen for a killed positive
            atomicOr(&hkw[ki >> 5], 1u << (ki & 31));
            float v = iou4(sbox[base + ki], sbox[base + j]);
            int gi = gtL[ki];
            if (g != gi && v > iou4(gtb[gi], gtb[g])) {
                atomicAdd(&cntA[ki], 1u);
                atomicAdd(&sumA[ki], -logf(1.5f - v) * __uint_as_float(scoreL[j]));
            }
        }
    }
    __syncthreads();

    // ---- pass 2: accumulation over kept selections (order-free) ----
    float ltpush = 0.f, ltpull = 0.f;
    int lqcnt = 0, lpcnt = 0;
    const u64 minkey = s_minkey;
    for (int i = tid; i < NN; i += STH) {
        if (st[i] != 1) continue;
        int g = gtL[i];
        u64 ky = make_key(scoreL[i], i);
        u64 fk = firstk[g];
        bool hkb = (hkw[i >> 5] >> (i & 31)) & 1u;
        bool add = (ky != minkey) || hkb;             // any(alive_p) at this selection
        int c = (int)cntA[i];
        bool hr = fk > ky;                            // earlier kept with same gt
        if (add && c > 0) ltpush += sumA[i] / (float)c;
        if (add) lqcnt += c;
        if (hr) ++lpcnt;                              // counted even when !add (matches ref)
        if (add && hr) {
            int r = (NN - 1) - (int)(fk & 0xffffffffu);
            float v = iou4(sbox[base + i], sbox[base + r]);
            ltpull += -logf(fmaxf(v, 1e-6f)) * __uint_as_float(scoreL[i]);
        }
    }
    ltpush = wredf(ltpush); ltpull = wredf(ltpull);
    lqcnt = wredi(lqcnt); lpcnt = wredi(lpcnt);
    if (lane == 0) {
        if (ltpush != 0.f) atomicAdd(&s_tpush, ltpush);
        if (ltpull != 0.f) atomicAdd(&s_tpull, ltpull);
        if (lqcnt) atomicAdd(&s_qcnt, lqcnt);
        if (lpcnt) atomicAdd(&s_pcnt, lpcnt);
    }
    __syncthreads();

    // ---- cross-image finalize: last-finishing block writes the B-mean ----
    if (tid == 0) {
        float valid = (s_pos > 1) ? 1.0f : 0.0f;
        float push_b = s_tpush / ((float)s_qcnt + 1e-6f) * valid;
        float pull_b = s_tpull / ((float)s_pcnt + 1e-6f) * valid;
        atomicAdd(&acc[0], push_b);
        atomicAdd(&acc[1], pull_b);
        __threadfence();
        u32 old = atomicAdd(ctr2, 1u);
        if (old == (u32)(B - 1)) {
            float ps = atomicAdd(&acc[0], 0.0f);
            float pl = atomicAdd(&acc[1], 0.0f);
            float inv = 1.0f / (float)B;
            out[0] = ps * inv * 1.0f;  // push_loss * PUSH_W
            out[1] = pl * inv * 1.0f;  // pull_loss * PULL_W
        }
    }
}

extern "C" void kernel_launch(void* const* d_in, const int* in_sizes, int n_in,
                              void* d_out, int out_size, void* d_ws, size_t ws_size,
                              hipStream_t stream) {
    // inputs: 0=gt_inds(B*N i32), 1=anchor_gt_inds(B*N i32),
    //         2=gt_bboxes(B*G*4 f32), 3=proposal_list(B*N*5 f32)
    const int B = in_sizes[0] / NN;
    const int* anchor_gt = (const int*)d_in[1];
    const float* gtb = (const float*)d_in[2];
    const float* props = (const float*)d_in[3];

    // ---- workspace layout (~0.6 MB for B=4; all regions 16B-multiple) ----
    char* w = (char*)d_ws;
    int* ecnt = (int*)w;                                  // B × 128 B (padded counters)
    float* acc = (float*)(w + (size_t)B * 128);           // 2 f32
    u32* ctr2 = (u32*)(w + (size_t)B * 128 + 8);
    size_t o = (size_t)B * 128 + 128;                     // memset region [0, o)
    float4* sbox = (float4*)(w + o);        o += (size_t)B * NN * 16;
    float* ssc = (float*)(w + o);           o += (size_t)B * NN * 4;
    int* sgt = (int*)(w + o);               o += (size_t)B * NN * 4;
    u32* edges = (u32*)(w + o);             o += (size_t)B * MAXE * 4;
    unsigned char* st_g = (unsigned char*)(w + o); o += (size_t)B * NN;
    u16* eoff_g = (u16*)(w + o);            o += (size_t)B * (NN + 2) * 2;
    u16* ent_g = (u16*)(w + o);

    hipMemsetAsync(d_ws, 0, (size_t)B * 128 + 128, stream);
    prep_kernel<<<dim3(B), dim3(STH), 0, stream>>>(anchor_gt, props, sbox, ssc, sgt);
    pair_kernel<<<dim3(B * NPAIR), dim3(256), 0, stream>>>(sbox, ssc, sgt, ecnt, edges);
    fix_kernel<<<dim3(B), dim3(STH), 0, stream>>>(sgt, ecnt, edges, st_g, eoff_g, ent_g);
    attr_kernel<<<dim3(B), dim3(STH), 0, stream>>>(sgt, gtb, sbox, ssc, ecnt, st_g, eoff_g, ent_g,
                                                   acc, ctr2, (float*)d_out, B);
}